// Round 2
// baseline (253.222 us; speedup 1.0000x reference)
//
#include <hip/hip_runtime.h>

#define B_ 64
#define C_ 3
#define H_ 384
#define W_ 384
#define HW_ (H_ * W_)

// Native clang vector type: __builtin_nontemporal_store requires a pointer to
// scalar or native vector (HIP's float2 class does not qualify).
typedef float f32x2 __attribute__((ext_vector_type(2)));

// Per-pixel bilinear setup: weights + gather offsets.
// Math is bit-identical to the previous (verified) kernel's per-pixel path.
struct Pix { float w00, w01, w10, w11; int o00, o01, o10, o11; };

__device__ __forceinline__ Pix pix_setup(
    float xg, float yg,
    float t00, float t01, float t02,
    float t10, float t11, float t12)
{
    float ix = fmaf(xg, t00, fmaf(yg, t01, t02)) + 191.5f;
    float iy = fmaf(xg, t10, fmaf(yg, t11, t12)) + 191.5f;

    float x0f = floorf(ix);
    float y0f = floorf(iy);
    float wx1 = ix - x0f;
    float wy1 = iy - y0f;
    float wx0 = 1.0f - wx1;
    float wy0 = 1.0f - wy1;
    float x1f = x0f + 1.0f;
    float y1f = y0f + 1.0f;

    bool vx0 = (x0f >= 0.0f) && (x0f < (float)W_);
    bool vx1 = (x1f >= 0.0f) && (x1f < (float)W_);
    bool vy0 = (y0f >= 0.0f) && (y0f < (float)H_);
    bool vy1 = (y1f >= 0.0f) && (y1f < (float)H_);

    int x0 = (int)fminf(fmaxf(x0f, 0.0f), (float)(W_ - 1));
    int x1 = (int)fminf(fmaxf(x1f, 0.0f), (float)(W_ - 1));
    int y0 = (int)fminf(fmaxf(y0f, 0.0f), (float)(H_ - 1));
    int y1 = (int)fminf(fmaxf(y1f, 0.0f), (float)(H_ - 1));

    Pix p;
    p.w00 = wx0 * wy0 * ((vx0 && vy0) ? 1.0f : 0.0f);
    p.w01 = wx1 * wy0 * ((vx1 && vy0) ? 1.0f : 0.0f);
    p.w10 = wx0 * wy1 * ((vx0 && vy1) ? 1.0f : 0.0f);
    p.w11 = wx1 * wy1 * ((vx1 && vy1) ? 1.0f : 0.0f);
    p.o00 = y0 * W_ + x0;
    p.o01 = y0 * W_ + x1;
    p.o10 = y1 * W_ + x0;
    p.o11 = y1 * W_ + x1;
    return p;
}

// One thread computes a 2x2 output quad (x,x+1) x (y,y+1).
// A 192-thread block covers exactly one full row-pair of one image:
// vertical input-row overlap becomes intra-thread/intra-block (L1-resident,
// block footprint ~4 rows x 3ch ~= 18KB < 32KB L1) instead of cross-CU.
__global__ __launch_bounds__(192) void affine_sample_kernel(
    const float* __restrict__ imgs,
    const float* __restrict__ theta,
    float* __restrict__ out)
{
    // XCD swizzle: give each XCD a contiguous run of row-pair blocks.
    // 12288 blocks / 8 = 1536 per XCD = 8 whole images per XCD, so each
    // image's gather working set stays in that XCD's L2.
    int nb = gridDim.x;                    // 12288 (multiple of 8)
    int bid = blockIdx.x;
    int sb = (bid & 7) * (nb >> 3) + (bid >> 3);

    int b  = sb / 192;                     // image (block-uniform)
    int yp = sb - b * 192;                 // row-pair within image
    b = __builtin_amdgcn_readfirstlane(b);
    int y = yp * 2;
    int x = threadIdx.x * 2;               // 192 threads * 2 = 384 = W

    const float* th = theta + b * 6;
    float t00 = th[0], t01 = th[1], t02 = th[2];
    float t10 = th[3], t11 = th[4], t12 = th[5];

    float xg = (float)x - 191.5f;          // (float)(x+1)-191.5f == xg+1.0f exactly
    float yg = (float)y - 191.5f;

    Pix pa = pix_setup(xg,        yg,        t00, t01, t02, t10, t11, t12); // (x  , y  )
    Pix pb = pix_setup(xg + 1.0f, yg,        t00, t01, t02, t10, t11, t12); // (x+1, y  )
    Pix pc = pix_setup(xg,        yg + 1.0f, t00, t01, t02, t10, t11, t12); // (x  , y+1)
    Pix pd = pix_setup(xg + 1.0f, yg + 1.0f, t00, t01, t02, t10, t11, t12); // (x+1, y+1)

    const float* bimg = imgs + (size_t)b * (C_ * HW_);
    float* bout = out + (size_t)b * (C_ * HW_) + y * W_ + x;

#pragma unroll
    for (int c = 0; c < C_; ++c) {
        const float* p = bimg + c * HW_;

        // 16 gathers issued before any consumer; duplicates across the quad
        // hit L1 (same input rows/lines).
        float a0 = p[pa.o00], a1 = p[pa.o01], a2 = p[pa.o10], a3 = p[pa.o11];
        float b0 = p[pb.o00], b1 = p[pb.o01], b2 = p[pb.o10], b3 = p[pb.o11];
        float c0 = p[pc.o00], c1 = p[pc.o01], c2 = p[pc.o10], c3 = p[pc.o11];
        float d0 = p[pd.o00], d1 = p[pd.o01], d2 = p[pd.o10], d3 = p[pd.o11];

        float ra = fmaf(a0, pa.w00, fmaf(a1, pa.w01, fmaf(a2, pa.w10, a3 * pa.w11)));
        float rb = fmaf(b0, pb.w00, fmaf(b1, pb.w01, fmaf(b2, pb.w10, b3 * pb.w11)));
        float rc = fmaf(c0, pc.w00, fmaf(c1, pc.w01, fmaf(c2, pc.w10, c3 * pc.w11)));
        float rd = fmaf(d0, pd.w00, fmaf(d1, pd.w01, fmaf(d2, pd.w10, d3 * pd.w11)));

        // Coalesced float2 nontemporal stores: output is write-once streaming,
        // keep it out of L2/LLC so the gather input stays resident.
        f32x2 top; top.x = ra; top.y = rb;
        f32x2 bot; bot.x = rc; bot.y = rd;
        __builtin_nontemporal_store(top, reinterpret_cast<f32x2*>(bout + c * HW_));
        __builtin_nontemporal_store(bot, reinterpret_cast<f32x2*>(bout + c * HW_ + W_));
    }
}

extern "C" void kernel_launch(void* const* d_in, const int* in_sizes, int n_in,
                              void* d_out, int out_size, void* d_ws, size_t ws_size,
                              hipStream_t stream) {
    const float* imgs = (const float*)d_in[0];
    const float* theta = (const float*)d_in[1];
    float* out = (float*)d_out;
    int blocks = B_ * (H_ / 2);               // 12288 row-pair blocks
    affine_sample_kernel<<<blocks, 192, 0, stream>>>(imgs, theta, out);
}

// Round 3
// 226.112 us; speedup vs baseline: 1.1199x; 1.1199x over previous
//
#include <hip/hip_runtime.h>

#define B_ 64
#define C_ 3
#define H_ 384
#define W_ 384
#define HW_ (H_ * W_)

// 1 output pixel per thread (R0 structure: 12 gathers up-front, 16-20 VGPR,
// 256-thread blocks) — but blocks now map to a 128x2 tile instead of a 256x1
// strip. The two output rows of a tile read ~the same input lines; having them
// on the SAME CU at the SAME time lets the duplicate misses merge in L1/MSHR
// instead of being issued twice from two different CUs (R0). The kernel is
// miss-throughput bound (VALUBusy 26%, HBM 22%, occupancy 75% in R0), so
// distinct-line-misses per CU is the thing to cut.
__global__ __launch_bounds__(256) void affine_sample_kernel(
    const float* __restrict__ imgs,
    const float* __restrict__ theta,
    float* __restrict__ out)
{
    // XCD swizzle: 36,864 blocks / 8 XCDs = 4,608 contiguous tiles per XCD
    // = exactly 8 whole images per XCD -> gather working set stays in-XCD L2.
    int nb = gridDim.x;                    // 36,864 (multiple of 8)
    int bid = blockIdx.x;
    int sb = (bid & 7) * (nb >> 3) + (bid >> 3);

    // Per image: 192 row-pairs x 3 x-tiles = 576 blocks. x-tile fastest so
    // consecutive sb walk a row-pair left-to-right, then the next row-pair:
    // vertically-adjacent tiles are close in time and on the same XCD.
    int b   = sb / 576;                    // image (SGPR arithmetic - uniform)
    int rem = sb - b * 576;
    int rp  = rem / 3;                     // row-pair index
    int xt  = rem - rp * 3;                // x-tile index

    int tid = threadIdx.x;
    int x = xt * 128 + (tid & 127);        // wave0/1: row y, wave2/3: row y+1
    int y = rp * 2 + (tid >> 7);

    const float* th = theta + b * 6;
    float t00 = th[0], t01 = th[1], t02 = th[2];
    float t10 = th[3], t11 = th[4], t12 = th[5];

    // Per-pixel math bit-identical to the verified R0 kernel.
    float xg = (float)x - 191.5f;
    float yg = (float)y - 191.5f;

    float ix = fmaf(xg, t00, fmaf(yg, t01, t02)) + 191.5f;
    float iy = fmaf(xg, t10, fmaf(yg, t11, t12)) + 191.5f;

    float x0f = floorf(ix);
    float y0f = floorf(iy);
    float wx1 = ix - x0f;
    float wy1 = iy - y0f;
    float wx0 = 1.0f - wx1;
    float wy0 = 1.0f - wy1;
    float x1f = x0f + 1.0f;
    float y1f = y0f + 1.0f;

    bool vx0 = (x0f >= 0.0f) && (x0f < (float)W_);
    bool vx1 = (x1f >= 0.0f) && (x1f < (float)W_);
    bool vy0 = (y0f >= 0.0f) && (y0f < (float)H_);
    bool vy1 = (y1f >= 0.0f) && (y1f < (float)H_);

    int x0 = (int)fminf(fmaxf(x0f, 0.0f), (float)(W_ - 1));
    int x1 = (int)fminf(fmaxf(x1f, 0.0f), (float)(W_ - 1));
    int y0 = (int)fminf(fmaxf(y0f, 0.0f), (float)(H_ - 1));
    int y1 = (int)fminf(fmaxf(y1f, 0.0f), (float)(H_ - 1));

    float w00 = wx0 * wy0 * ((vx0 && vy0) ? 1.0f : 0.0f);
    float w01 = wx1 * wy0 * ((vx1 && vy0) ? 1.0f : 0.0f);
    float w10 = wx0 * wy1 * ((vx0 && vy1) ? 1.0f : 0.0f);
    float w11 = wx1 * wy1 * ((vx1 && vy1) ? 1.0f : 0.0f);

    int o00 = y0 * W_ + x0;
    int o01 = y0 * W_ + x1;
    int o10 = y1 * W_ + x0;
    int o11 = y1 * W_ + x1;

    const float* bimg = imgs + (size_t)b * (C_ * HW_);
    float* bout = out + (size_t)b * (C_ * HW_) + y * W_ + x;

    // ---- issue ALL 12 gathers before any consumer (max per-thread MLP) ----
    float v[C_][4];
#pragma unroll
    for (int c = 0; c < C_; ++c) {
        const float* p = bimg + c * HW_;
        v[c][0] = p[o00];
        v[c][1] = p[o01];
        v[c][2] = p[o10];
        v[c][3] = p[o11];
    }

#pragma unroll
    for (int c = 0; c < C_; ++c) {
        float r = fmaf(v[c][0], w00, fmaf(v[c][1], w01,
                  fmaf(v[c][2], w10, v[c][3] * w11)));
        bout[c * HW_] = r;
    }
}

extern "C" void kernel_launch(void* const* d_in, const int* in_sizes, int n_in,
                              void* d_out, int out_size, void* d_ws, size_t ws_size,
                              hipStream_t stream) {
    const float* imgs = (const float*)d_in[0];
    const float* theta = (const float*)d_in[1];
    float* out = (float*)d_out;
    int total = B_ * H_ * W_;                 // 9,437,184
    affine_sample_kernel<<<total / 256, 256, 0, stream>>>(imgs, theta, out);
}

// Round 4
// 208.652 us; speedup vs baseline: 1.2136x; 1.0837x over previous
//
#include <hip/hip_runtime.h>

#define B_ 64
#define C_ 3
#define H_ 384
#define W_ 384
#define HW_ (H_ * W_)

// Native clang 2-float vector with 4-byte alignment: the horizontal tap pair
// (x0, x0+1) is contiguous, so one global_load_dwordx2 replaces two dword
// gathers. gfx950 handles 4B-aligned dwordx2 (HW unaligned-access mode).
typedef float f32x2 __attribute__((ext_vector_type(2)));
typedef f32x2 __attribute__((aligned(4))) f32x2_u;

// Theory: kernel is VMEM-request-throughput bound (R3 showed miss-count cut
// is neutral; R2 showed concurrency is saturated). Each gather instruction
// costs ~#distinct-lines tag lookups in the TCP regardless of hit/miss.
// Halve the gather-instruction count: 12 scalar gathers -> 6 pair gathers.
__global__ __launch_bounds__(256) void affine_sample_kernel(
    const float* __restrict__ imgs,
    const float* __restrict__ theta,
    float* __restrict__ out)
{
    // XCD swizzle: 36,864 blocks / 8 XCDs = 4,608 contiguous tiles per XCD
    // = exactly 8 whole images per XCD -> gather working set stays in-XCD L2.
    int nb = gridDim.x;                    // 36,864 (multiple of 8)
    int bid = blockIdx.x;
    int sb = (bid & 7) * (nb >> 3) + (bid >> 3);

    // 128x2 tile per block (R3 mapping, neutral-to-slightly-better vs 256x1).
    int b   = sb / 576;                    // image (block-uniform)
    int rem = sb - b * 576;
    int rp  = rem / 3;                     // row-pair index
    int xt  = rem - rp * 3;                // x-tile index

    int tid = threadIdx.x;
    int x = xt * 128 + (tid & 127);        // wave0/1: row y, wave2/3: row y+1
    int y = rp * 2 + (tid >> 7);

    const float* th = theta + b * 6;
    float t00 = th[0], t01 = th[1], t02 = th[2];
    float t10 = th[3], t11 = th[4], t12 = th[5];

    // Per-pixel math bit-identical to the verified R0/R3 kernels.
    float xg = (float)x - 191.5f;
    float yg = (float)y - 191.5f;

    float ix = fmaf(xg, t00, fmaf(yg, t01, t02)) + 191.5f;
    float iy = fmaf(xg, t10, fmaf(yg, t11, t12)) + 191.5f;

    float x0f = floorf(ix);
    float y0f = floorf(iy);
    float wx1 = ix - x0f;
    float wy1 = iy - y0f;
    float wx0 = 1.0f - wx1;
    float wy0 = 1.0f - wy1;
    float x1f = x0f + 1.0f;
    float y1f = y0f + 1.0f;

    bool vx0 = (x0f >= 0.0f) && (x0f < (float)W_);
    bool vx1 = (x1f >= 0.0f) && (x1f < (float)W_);
    bool vy0 = (y0f >= 0.0f) && (y0f < (float)H_);
    bool vy1 = (y1f >= 0.0f) && (y1f < (float)H_);

    int x0 = (int)fminf(fmaxf(x0f, 0.0f), (float)(W_ - 1));
    int x1 = (int)fminf(fmaxf(x1f, 0.0f), (float)(W_ - 1));
    int y0 = (int)fminf(fmaxf(y0f, 0.0f), (float)(H_ - 1));
    int y1 = (int)fminf(fmaxf(y1f, 0.0f), (float)(H_ - 1));

    // Pair base: clamp to [0, W-2] so the 8B load stays inside the row's
    // channel plane (max offset = 383*384+382 -> last byte == plane end).
    int xb = (int)fminf(fmaxf(x0f, 0.0f), (float)(W_ - 2));

    // Tap selection from the pair. Verified case-by-case:
    //  x0f in [0,W-2]: x0==xb -> v00=pair.x; x1=xb+1 -> v01=pair.y  (exact)
    //  x0f == W-1:     xb=W-2 -> v00=pair.y=p[W-1] (exact); v01 weight=0
    //  x0f == -1:      x0=0==xb -> v00 weight=0; x1=0==xb -> v01=pair.x=p[0] (exact)
    //  x0f out of range further: both weights 0, any in-bounds value fine.
    bool selx0 = (x0 == xb);
    bool selx1 = (x1 == xb);

    float w00 = wx0 * wy0 * ((vx0 && vy0) ? 1.0f : 0.0f);
    float w01 = wx1 * wy0 * ((vx1 && vy0) ? 1.0f : 0.0f);
    float w10 = wx0 * wy1 * ((vx0 && vy1) ? 1.0f : 0.0f);
    float w11 = wx1 * wy1 * ((vx1 && vy1) ? 1.0f : 0.0f);

    int oT = y0 * W_ + xb;                 // top-row pair
    int oB = y1 * W_ + xb;                 // bottom-row pair

    const float* bimg = imgs + (size_t)b * (C_ * HW_);
    float* bout = out + (size_t)b * (C_ * HW_) + y * W_ + x;

    // ---- issue ALL 6 pair-gathers before any consumer ----
    f32x2 vt[C_], vb[C_];
#pragma unroll
    for (int c = 0; c < C_; ++c) {
        const float* p = bimg + c * HW_;
        vt[c] = *reinterpret_cast<const f32x2_u*>(p + oT);
        vb[c] = *reinterpret_cast<const f32x2_u*>(p + oB);
    }

#pragma unroll
    for (int c = 0; c < C_; ++c) {
        float v00 = selx0 ? vt[c].x : vt[c].y;
        float v01 = selx1 ? vt[c].x : vt[c].y;
        float v10 = selx0 ? vb[c].x : vb[c].y;
        float v11 = selx1 ? vb[c].x : vb[c].y;
        float r = fmaf(v00, w00, fmaf(v01, w01,
                  fmaf(v10, w10, v11 * w11)));
        bout[c * HW_] = r;
    }
}

extern "C" void kernel_launch(void* const* d_in, const int* in_sizes, int n_in,
                              void* d_out, int out_size, void* d_ws, size_t ws_size,
                              hipStream_t stream) {
    const float* imgs = (const float*)d_in[0];
    const float* theta = (const float*)d_in[1];
    float* out = (float*)d_out;
    int total = B_ * H_ * W_;                 // 9,437,184
    affine_sample_kernel<<<total / 256, 256, 0, stream>>>(imgs, theta, out);
}